// Round 5
// baseline (311.509 us; speedup 1.0000x reference)
//
#include <hip/hip_runtime.h>
#include <math.h>

#define DMODEL 4096
#define THREED 12288
#define NHEAD 32
#define HDIM 128
#define NB 8
#define NPAGES 32
#define PAGEK 128

#if __has_builtin(__builtin_amdgcn_exp2f)
#define FAST_EXP2(x) __builtin_amdgcn_exp2f(x)
#else
#define FAST_EXP2(x) exp2f(x)
#endif

// log2(e) / sqrt(128)
#define SCALE_LOG2E (0.08838834764831845f * 1.44269504088896340736f)

// ---------------------------------------------------------------------------
// Skinny GEMM partial: part[s][b][col] = sum_{k in chunk s} X[b][k]*W[k][col]
// X: [8][K] (wave-uniform scalar loads), W: [K][N] row-major.
// Each thread owns 2 columns (float2 loads of W). k-split over blockIdx.y.
// ---------------------------------------------------------------------------
__global__ __launch_bounds__(256) void gemm_skinny_partial(
    const float* __restrict__ X, const float* __restrict__ W,
    float* __restrict__ part, int K, int N, int kchunk) {
  const int col = (blockIdx.x * 256 + threadIdx.x) * 2;
  const int k0 = blockIdx.y * kchunk;

  float2 acc[8];
  #pragma unroll
  for (int b = 0; b < 8; ++b) acc[b] = make_float2(0.f, 0.f);

  const float* wp = W + (size_t)k0 * N + col;
  const float* xp = X + k0;

  #pragma unroll 8
  for (int k = 0; k < kchunk; ++k) {
    const float2 w = *(const float2*)(wp + (size_t)k * N);
    #pragma unroll
    for (int b = 0; b < 8; ++b) {
      const float xv = xp[b * K + k];  // wave-uniform -> s_load, SGPR operand
      acc[b].x += xv * w.x;
      acc[b].y += xv * w.y;
    }
  }
  #pragma unroll
  for (int b = 0; b < 8; ++b)
    *(float2*)(part + ((size_t)blockIdx.y * 8 + b) * N + col) = acc[b];
}

// out[b][col4] = bias[col4] + sum_s part[s][b][col4]   (float4 per thread)
__global__ __launch_bounds__(256) void gemm_skinny_reduce(
    const float* __restrict__ part, const float* __restrict__ bias,
    float* __restrict__ out, int N, int ksplit) {
  int idx = blockIdx.x * 256 + threadIdx.x;  // over 8*N/4
  int n4 = N >> 2;
  int b = idx / n4, col = (idx - b * n4) * 4;
  float4 acc = *(const float4*)(bias + col);
  for (int s = 0; s < ksplit; ++s) {
    const float4 p = *(const float4*)(part + ((size_t)s * 8 + b) * N + col);
    acc.x += p.x;
    acc.y += p.y;
    acc.z += p.z;
    acc.w += p.w;
  }
  *(float4*)(out + (size_t)b * N + col) = acc;
}

// ---------------------------------------------------------------------------
// Monolithic attention: one 512-thread block (8 waves) per (head, batch).
// Phase A: reduce gemm1 partials in-block -> q, k_cur, v_cur (LDS).
// Phase B: loop 32 pages; each wave owns 16 keys/page (2 per iter via lane
//          halves, float4 per lane); accumulate numerator/denominator in regs.
// Phase C: LDS-combine 16 streams, fold in current-token term, divide, write.
// ---------------------------------------------------------------------------
__global__ __launch_bounds__(512) void attn_mono(
    const float* __restrict__ g1p,     // [32][8][12288] qkv partials
    const float* __restrict__ b_attn,  // [12288]
    const float* __restrict__ k_cache, // [32][8][32][128][128]
    const float* __restrict__ v_cache,
    float* __restrict__ yat) {         // [8][4096]
  const int h = blockIdx.x;
  const int b = blockIdx.y;
  const int tid = threadIdx.x;

  __shared__ float q_lds[HDIM], kc_lds[HDIM], vc_lds[HDIM];
  __shared__ float y16[16][HDIM];
  __shared__ float den16[16];
  __shared__ float wn_lds;

  // ---- Phase A: q / k_cur / v_cur from gemm1 partials + bias ----
  if (tid < 384) {
    const int which = tid >> 7;        // 0=q, 1=k, 2=v
    const int d = tid & 127;
    const int col = which * DMODEL + h * HDIM + d;
    float val = b_attn[col];
    #pragma unroll 8
    for (int s = 0; s < 32; ++s)
      val += g1p[((size_t)s * 8 + b) * THREED + col];
    if (which == 0) q_lds[d] = val;
    else if (which == 1) kc_lds[d] = val;
    else vc_lds[d] = val;
  }
  __syncthreads();

  // current-token score (wave 0 only; visible after Phase C barrier)
  if (tid < 64) {
    float s0 = q_lds[tid] * kc_lds[tid] + q_lds[tid + 64] * kc_lds[tid + 64];
    s0 += __shfl_xor(s0, 1, 64);
    s0 += __shfl_xor(s0, 2, 64);
    s0 += __shfl_xor(s0, 4, 64);
    s0 += __shfl_xor(s0, 8, 64);
    s0 += __shfl_xor(s0, 16, 64);
    s0 += __shfl_xor(s0, 32, 64);
    if (tid == 0) wn_lds = FAST_EXP2(s0 * SCALE_LOG2E);
  }

  // ---- Phase B: page loop ----
  const int wv = tid >> 6;
  const int lane = tid & 63;
  const int half = lane >> 5;
  const int l31 = lane & 31;
  const float4 qf = *(const float4*)&q_lds[4 * l31];

  float4 yacc = {0.f, 0.f, 0.f, 0.f};
  float den = 0.f;

  for (int p = 0; p < NPAGES; ++p) {
    const size_t base = ((((size_t)p * NB + b) * NHEAD + h) * PAGEK) * HDIM;
    const float* kp = k_cache + base;
    const float* vp = v_cache + base;
    #pragma unroll 8
    for (int i = 0; i < 8; ++i) {
      const int key = wv * 16 + i * 2 + half;
      const float4 kf = *(const float4*)(kp + key * HDIM + 4 * l31);
      const float4 vf = *(const float4*)(vp + key * HDIM + 4 * l31);
      float s = qf.x * kf.x + qf.y * kf.y + qf.z * kf.z + qf.w * kf.w;
      s += __shfl_xor(s, 1, 64);
      s += __shfl_xor(s, 2, 64);
      s += __shfl_xor(s, 4, 64);
      s += __shfl_xor(s, 8, 64);
      s += __shfl_xor(s, 16, 64);
      const float w = FAST_EXP2(s * SCALE_LOG2E);
      den += w;
      yacc.x += w * vf.x;
      yacc.y += w * vf.y;
      yacc.z += w * vf.z;
      yacc.w += w * vf.w;
    }
  }

  // ---- Phase C: combine 16 (wave,half) streams, finalize ----
  const int row = wv * 2 + half;
  *(float4*)&y16[row][4 * l31] = yacc;
  if (l31 == 0) den16[row] = den;
  __syncthreads();

  if (tid < HDIM) {
    float y = 0.f;
    #pragma unroll
    for (int r = 0; r < 16; ++r) y += y16[r][tid];
    float dt = 0.f;
    #pragma unroll
    for (int r = 0; r < 16; ++r) dt += den16[r];
    const float wn = wn_lds;
    yat[(size_t)b * DMODEL + h * HDIM + tid] =
        (y + wn * vc_lds[tid]) / (dt + wn);
  }
}

extern "C" void kernel_launch(void* const* d_in, const int* in_sizes, int n_in,
                              void* d_out, int out_size, void* d_ws,
                              size_t ws_size, hipStream_t stream) {
  const float* x = (const float*)d_in[0];
  const float* k_cache = (const float*)d_in[1];
  const float* v_cache = (const float*)d_in[2];
  const float* w_attn = (const float*)d_in[3];
  const float* b_attn = (const float*)d_in[4];
  const float* w_proj = (const float*)d_in[5];
  const float* b_proj = (const float*)d_in[6];
  float* out = (float*)d_out;
  float* ws = (float*)d_ws;

  // workspace layout (floats)
  float* g1p = ws;                    // 32*8*12288 = 3145728
  float* yat = g1p + 32 * 8 * THREED; // 8*4096     = 32768
  float* g2p = yat + NB * DMODEL;     // 64*8*4096  = 2097152

  // 1) qkv partials: x @ w_attn   (2 cols/thread, K=4096 split 32x128)
  gemm_skinny_partial<<<dim3(THREED / 512, 32), 256, 0, stream>>>(
      x, w_attn, g1p, DMODEL, THREED, 128);

  // 2) monolithic attention (in-block qkv reduce + 32-page loop + finalize)
  attn_mono<<<dim3(NHEAD, NB), 512, 0, stream>>>(
      g1p, b_attn, k_cache, v_cache, yat);

  // 3) out = yat @ w_proj + b_proj  (2 cols/thread, K=4096 split 64x64)
  gemm_skinny_partial<<<dim3(DMODEL / 512, 64), 256, 0, stream>>>(
      yat, w_proj, g2p, DMODEL, DMODEL, 64);
  gemm_skinny_reduce<<<dim3(NB * DMODEL / 1024), 256, 0, stream>>>(
      g2p, b_proj, out, DMODEL, 64);
}

// Round 6
// 272.989 us; speedup vs baseline: 1.1411x; 1.1411x over previous
//
#include <hip/hip_runtime.h>
#include <math.h>

#define DMODEL 4096
#define THREED 12288
#define NHEAD 32
#define HDIM 128
#define NB 8
#define NPAGES 32
#define PAGEK 128
#define KSPLIT1 32

#if __has_builtin(__builtin_amdgcn_exp2f)
#define FAST_EXP2(x) __builtin_amdgcn_exp2f(x)
#else
#define FAST_EXP2(x) exp2f(x)
#endif

// log2(e) / sqrt(128)
#define SCALE_LOG2E (0.08838834764831845f * 1.44269504088896340736f)

// ---------------------------------------------------------------------------
// Skinny GEMM partial: part[s][b][col] = sum_{k in chunk s} X[b][k]*W[k][col]
// X: [8][K] (wave-uniform scalar loads), W: [K][N] row-major.
// Each thread owns 2 columns (float2 loads of W). k-split over blockIdx.y.
// ---------------------------------------------------------------------------
__global__ __launch_bounds__(256) void gemm_skinny_partial(
    const float* __restrict__ X, const float* __restrict__ W,
    float* __restrict__ part, int K, int N, int kchunk) {
  const int col = (blockIdx.x * 256 + threadIdx.x) * 2;
  const int k0 = blockIdx.y * kchunk;

  float2 acc[8];
  #pragma unroll
  for (int b = 0; b < 8; ++b) acc[b] = make_float2(0.f, 0.f);

  const float* wp = W + (size_t)k0 * N + col;
  const float* xp = X + k0;

  #pragma unroll 8
  for (int k = 0; k < kchunk; ++k) {
    const float2 w = *(const float2*)(wp + (size_t)k * N);
    #pragma unroll
    for (int b = 0; b < 8; ++b) {
      const float xv = xp[b * K + k];  // wave-uniform -> s_load, SGPR operand
      acc[b].x += xv * w.x;
      acc[b].y += xv * w.y;
    }
  }
  #pragma unroll
  for (int b = 0; b < 8; ++b)
    *(float2*)(part + ((size_t)blockIdx.y * 8 + b) * N + col) = acc[b];
}

// out[b][col4] = bias[col4] + sum_s part[s][b][col4]   (float4 per thread)
__global__ __launch_bounds__(256) void gemm_skinny_reduce(
    const float* __restrict__ part, const float* __restrict__ bias,
    float* __restrict__ out, int N, int ksplit) {
  int idx = blockIdx.x * 256 + threadIdx.x;  // over 8*N/4
  int n4 = N >> 2;
  int b = idx / n4, col = (idx - b * n4) * 4;
  float4 acc = *(const float4*)(bias + col);
  for (int s = 0; s < ksplit; ++s) {
    const float4 p = *(const float4*)(part + ((size_t)s * 8 + b) * N + col);
    acc.x += p.x;
    acc.y += p.y;
    acc.z += p.z;
    acc.w += p.w;
  }
  *(float4*)(out + (size_t)b * N + col) = acc;
}

// ---------------------------------------------------------------------------
// Attention partial: one block per (page, head, batch). 256 threads = 4 waves.
// Phase A: reduce this block's q-slice from gemm1 partials (L2-hot, 16 KB).
// Phase B: 16 iters, 2 keys/iter via lane halves, float4 per lane (= R2 loop).
// ---------------------------------------------------------------------------
__global__ __launch_bounds__(256) void attn_partial(
    const float* __restrict__ g1p,      // [32][8][12288] qkv partials
    const float* __restrict__ b_attn,   // [12288]
    const float* __restrict__ k_cache,  // [32][8][32][128][128]
    const float* __restrict__ v_cache,
    float* __restrict__ part_y,         // [8*32*32][128]
    float* __restrict__ part_den) {     // [8*32*32]
  const int page = blockIdx.x;
  const int h = blockIdx.y;
  const int b = blockIdx.z;
  const int tid = threadIdx.x;
  const int wave = tid >> 6;
  const int lane = tid & 63;
  const int half = lane >> 5;
  const int l31 = lane & 31;

  __shared__ float q_lds[HDIM];

  // ---- Phase A: q[h*128+tid] = bias + sum_s partial[s] (same order as R2) --
  if (tid < HDIM) {
    const int col = h * HDIM + tid;
    float val = b_attn[col];
    #pragma unroll
    for (int s = 0; s < KSPLIT1; ++s)
      val += g1p[((size_t)s * 8 + b) * THREED + col];
    q_lds[tid] = val;
  }
  __syncthreads();

  const float4 qf = *(const float4*)&q_lds[4 * l31];

  const size_t base = ((((size_t)page * NB + b) * NHEAD + h) * PAGEK) * HDIM;
  const float* kp = k_cache + base;
  const float* vp = v_cache + base;

  float4 yacc = {0.f, 0.f, 0.f, 0.f};
  float den = 0.f;

  #pragma unroll 4
  for (int i = 0; i < 16; ++i) {
    const int key = wave * 32 + i * 2 + half;
    const float4 kf = *(const float4*)(kp + key * HDIM + 4 * l31);
    const float4 vf = *(const float4*)(vp + key * HDIM + 4 * l31);
    float s = qf.x * kf.x + qf.y * kf.y + qf.z * kf.z + qf.w * kf.w;
    s += __shfl_xor(s, 1, 64);
    s += __shfl_xor(s, 2, 64);
    s += __shfl_xor(s, 4, 64);
    s += __shfl_xor(s, 8, 64);
    s += __shfl_xor(s, 16, 64);
    const float w = FAST_EXP2(s * SCALE_LOG2E);
    den += w;
    yacc.x += w * vf.x;
    yacc.y += w * vf.y;
    yacc.z += w * vf.z;
    yacc.w += w * vf.w;
  }

  __shared__ float y_lds[8][HDIM];
  __shared__ float d_lds[8];
  const int row = wave * 2 + half;
  *(float4*)&y_lds[row][4 * l31] = yacc;
  if (l31 == 0) d_lds[row] = den;
  __syncthreads();

  if (tid < HDIM) {
    float y = 0.f;
    #pragma unroll
    for (int r = 0; r < 8; ++r) y += y_lds[r][tid];
    const int bhp = (b * NHEAD + h) * NPAGES + page;
    part_y[(size_t)bhp * HDIM + tid] = y;
    if (tid == 0) {
      float dd = 0.f;
      #pragma unroll
      for (int r = 0; r < 8; ++r) dd += d_lds[r];
      part_den[bhp] = dd;
    }
  }
}

// ---------------------------------------------------------------------------
// Attention reduce: per (b,h). Phase A reduces q/k_cur/v_cur slices from the
// gemm1 partials (L3-hot), then combines 32 page partials + current token.
// ---------------------------------------------------------------------------
__global__ __launch_bounds__(128) void attn_reduce(
    const float* __restrict__ g1p,     // [32][8][12288]
    const float* __restrict__ b_attn,  // [12288]
    const float* __restrict__ part_y, const float* __restrict__ part_den,
    float* __restrict__ yattn) {  // [8][4096]
  const int h = blockIdx.x;
  const int b = blockIdx.y;
  const int d = threadIdx.x;
  const int bh = b * NHEAD + h;

  // ---- Phase A: q, k_cur, v_cur for dim d (same summation order) ----
  const int col = h * HDIM + d;
  float qv = b_attn[col];
  float kc = b_attn[DMODEL + col];
  float vc = b_attn[2 * DMODEL + col];
  #pragma unroll 8
  for (int s = 0; s < KSPLIT1; ++s) {
    const size_t base = ((size_t)s * 8 + b) * THREED + col;
    qv += g1p[base];
    kc += g1p[base + DMODEL];
    vc += g1p[base + 2 * DMODEL];
  }

  float y = 0.f;
  #pragma unroll 4
  for (int p = 0; p < NPAGES; ++p)
    y += part_y[((size_t)bh * NPAGES + p) * HDIM + d];
  float den = 0.f;
  #pragma unroll 4
  for (int p = 0; p < NPAGES; ++p) den += part_den[bh * NPAGES + p];

  __shared__ float red[HDIM];
  red[d] = qv * kc;
  __syncthreads();
  for (int s = 64; s > 0; s >>= 1) {
    if (d < s) red[d] += red[d + s];
    __syncthreads();
  }
  const float wn = FAST_EXP2(red[0] * SCALE_LOG2E);
  y = (y + wn * vc) / (den + wn);
  yattn[(size_t)b * DMODEL + h * HDIM + d] = y;
}

extern "C" void kernel_launch(void* const* d_in, const int* in_sizes, int n_in,
                              void* d_out, int out_size, void* d_ws,
                              size_t ws_size, hipStream_t stream) {
  const float* x = (const float*)d_in[0];
  const float* k_cache = (const float*)d_in[1];
  const float* v_cache = (const float*)d_in[2];
  const float* w_attn = (const float*)d_in[3];
  const float* b_attn = (const float*)d_in[4];
  const float* w_proj = (const float*)d_in[5];
  const float* b_proj = (const float*)d_in[6];
  float* out = (float*)d_out;
  float* ws = (float*)d_ws;

  // workspace layout (floats)
  float* g1p = ws;                    // 32*8*12288 = 3145728
  float* apy = g1p + 32 * 8 * THREED; // 8192*128   = 1048576
  float* apd = apy + 8192 * HDIM;     // 8192
  float* yat = apd + 8192;            // 8*4096     = 32768
  float* g2p = yat + NB * DMODEL;     // 64*8*4096  = 2097152

  // 1) qkv partials: x @ w_attn  (2 cols/thread, K=4096 split 32x128)
  gemm_skinny_partial<<<dim3(THREED / 512, KSPLIT1), 256, 0, stream>>>(
      x, w_attn, g1p, DMODEL, THREED, 128);

  // 2) paged attention partials (q reduced in-block) + reduce
  attn_partial<<<dim3(NPAGES, NHEAD, NB), 256, 0, stream>>>(
      g1p, b_attn, k_cache, v_cache, apy, apd);
  attn_reduce<<<dim3(NHEAD, NB), 128, 0, stream>>>(
      g1p, b_attn, apy, apd, yat);

  // 3) out = yat @ w_proj + b_proj  (2 cols/thread, K=4096 split 64x64)
  gemm_skinny_partial<<<dim3(DMODEL / 512, 64), 256, 0, stream>>>(
      yat, w_proj, g2p, DMODEL, DMODEL, 64);
  gemm_skinny_reduce<<<dim3(NB * DMODEL / 1024), 256, 0, stream>>>(
      g2p, b_proj, out, DMODEL, 64);
}

// Round 8
// 252.365 us; speedup vs baseline: 1.2344x; 1.0817x over previous
//
#include <hip/hip_runtime.h>
#include <math.h>

#define DMODEL 4096
#define THREED 12288
#define NHEAD 32
#define HDIM 128
#define NB 8
#define NPAGES 32
#define PAGEK 128
#define KSPLIT1 32

#if __has_builtin(__builtin_amdgcn_exp2f)
#define FAST_EXP2(x) __builtin_amdgcn_exp2f(x)
#else
#define FAST_EXP2(x) exp2f(x)
#endif

// log2(e) / sqrt(128)
#define SCALE_LOG2E (0.08838834764831845f * 1.44269504088896340736f)

typedef float f32x4 __attribute__((ext_vector_type(4)));
typedef float f32x2 __attribute__((ext_vector_type(2)));

__device__ __forceinline__ float4 nt_load4(const float* p) {
  f32x4 v = __builtin_nontemporal_load((const f32x4*)p);
  return make_float4(v.x, v.y, v.z, v.w);
}
__device__ __forceinline__ float2 nt_load2(const float* p) {
  f32x2 v = __builtin_nontemporal_load((const f32x2*)p);
  return make_float2(v.x, v.y);
}

// ---------------------------------------------------------------------------
// Skinny GEMM partial: part[s][b][col] = sum_{k in chunk s} X[b][k]*W[k][col]
// X: [8][K] (wave-uniform scalar loads), W: [K][N] row-major, streamed nt.
// Each thread owns 2 columns (float2 loads of W). k-split over blockIdx.y.
// ---------------------------------------------------------------------------
__global__ __launch_bounds__(256) void gemm_skinny_partial(
    const float* __restrict__ X, const float* __restrict__ W,
    float* __restrict__ part, int K, int N, int kchunk) {
  const int col = (blockIdx.x * 256 + threadIdx.x) * 2;
  const int k0 = blockIdx.y * kchunk;

  float2 acc[8];
  #pragma unroll
  for (int b = 0; b < 8; ++b) acc[b] = make_float2(0.f, 0.f);

  const float* wp = W + (size_t)k0 * N + col;
  const float* xp = X + k0;

  #pragma unroll 8
  for (int k = 0; k < kchunk; ++k) {
    const float2 w = nt_load2(wp + (size_t)k * N);
    #pragma unroll
    for (int b = 0; b < 8; ++b) {
      const float xv = xp[b * K + k];  // wave-uniform -> s_load, SGPR operand
      acc[b].x += xv * w.x;
      acc[b].y += xv * w.y;
    }
  }
  #pragma unroll
  for (int b = 0; b < 8; ++b)
    *(float2*)(part + ((size_t)blockIdx.y * 8 + b) * N + col) = acc[b];
}

// out[b][col4] = bias[col4] + sum_s part[s][b][col4]   (float4 per thread)
__global__ __launch_bounds__(256) void gemm_skinny_reduce(
    const float* __restrict__ part, const float* __restrict__ bias,
    float* __restrict__ out, int N, int ksplit) {
  int idx = blockIdx.x * 256 + threadIdx.x;  // over 8*N/4
  int n4 = N >> 2;
  int b = idx / n4, col = (idx - b * n4) * 4;
  float4 acc = *(const float4*)(bias + col);
  for (int s = 0; s < ksplit; ++s) {
    const float4 p = *(const float4*)(part + ((size_t)s * 8 + b) * N + col);
    acc.x += p.x;
    acc.y += p.y;
    acc.z += p.z;
    acc.w += p.w;
  }
  *(float4*)(out + (size_t)b * N + col) = acc;
}

// ---------------------------------------------------------------------------
// Attention partial: one block per (page, head, batch). 256 threads = 4 waves.
// Phase A: reduce this block's q-slice from gemm1 partials (L2/L3-hot).
// Phase B: 16 iters, 2 keys/iter via lane halves, float4 nt loads of K/V.
// ---------------------------------------------------------------------------
__global__ __launch_bounds__(256) void attn_partial(
    const float* __restrict__ g1p,      // [32][8][12288] qkv partials
    const float* __restrict__ b_attn,   // [12288]
    const float* __restrict__ k_cache,  // [32][8][32][128][128]
    const float* __restrict__ v_cache,
    float* __restrict__ part_y,         // [8*32*32][128]
    float* __restrict__ part_den) {     // [8*32*32]
  const int page = blockIdx.x;
  const int h = blockIdx.y;
  const int b = blockIdx.z;
  const int tid = threadIdx.x;
  const int wave = tid >> 6;
  const int lane = tid & 63;
  const int half = lane >> 5;
  const int l31 = lane & 31;

  __shared__ float q_lds[HDIM];

  // ---- Phase A: q[h*128+tid] = bias + sum_s partial[s] ----
  if (tid < HDIM) {
    const int col = h * HDIM + tid;
    float val = b_attn[col];
    #pragma unroll
    for (int s = 0; s < KSPLIT1; ++s)
      val += g1p[((size_t)s * 8 + b) * THREED + col];
    q_lds[tid] = val;
  }
  __syncthreads();

  const float4 qf = *(const float4*)&q_lds[4 * l31];

  const size_t base = ((((size_t)page * NB + b) * NHEAD + h) * PAGEK) * HDIM;
  const float* kp = k_cache + base;
  const float* vp = v_cache + base;

  float4 yacc = {0.f, 0.f, 0.f, 0.f};
  float den = 0.f;

  #pragma unroll 4
  for (int i = 0; i < 16; ++i) {
    const int key = wave * 32 + i * 2 + half;
    const float4 kf = nt_load4(kp + key * HDIM + 4 * l31);
    const float4 vf = nt_load4(vp + key * HDIM + 4 * l31);
    float s = qf.x * kf.x + qf.y * kf.y + qf.z * kf.z + qf.w * kf.w;
    s += __shfl_xor(s, 1, 64);
    s += __shfl_xor(s, 2, 64);
    s += __shfl_xor(s, 4, 64);
    s += __shfl_xor(s, 8, 64);
    s += __shfl_xor(s, 16, 64);
    const float w = FAST_EXP2(s * SCALE_LOG2E);
    den += w;
    yacc.x += w * vf.x;
    yacc.y += w * vf.y;
    yacc.z += w * vf.z;
    yacc.w += w * vf.w;
  }

  __shared__ float y_lds[8][HDIM];
  __shared__ float d_lds[8];
  const int row = wave * 2 + half;
  *(float4*)&y_lds[row][4 * l31] = yacc;
  if (l31 == 0) d_lds[row] = den;
  __syncthreads();

  if (tid < HDIM) {
    float y = 0.f;
    #pragma unroll
    for (int r = 0; r < 8; ++r) y += y_lds[r][tid];
    const int bhp = (b * NHEAD + h) * NPAGES + page;
    part_y[(size_t)bhp * HDIM + tid] = y;
    if (tid == 0) {
      float dd = 0.f;
      #pragma unroll
      for (int r = 0; r < 8; ++r) dd += d_lds[r];
      part_den[bhp] = dd;
    }
  }
}

// ---------------------------------------------------------------------------
// Attention reduce: per (b,h). Phase A reduces q/k_cur/v_cur slices from the
// gemm1 partials (L3-hot), then combines 32 page partials + current token.
// ---------------------------------------------------------------------------
__global__ __launch_bounds__(128) void attn_reduce(
    const float* __restrict__ g1p,     // [32][8][12288]
    const float* __restrict__ b_attn,  // [12288]
    const float* __restrict__ part_y, const float* __restrict__ part_den,
    float* __restrict__ yattn) {  // [8][4096]
  const int h = blockIdx.x;
  const int b = blockIdx.y;
  const int d = threadIdx.x;
  const int bh = b * NHEAD + h;

  // ---- Phase A: q, k_cur, v_cur for dim d (same summation order) ----
  const int col = h * HDIM + d;
  float qv = b_attn[col];
  float kc = b_attn[DMODEL + col];
  float vc = b_attn[2 * DMODEL + col];
  #pragma unroll 8
  for (int s = 0; s < KSPLIT1; ++s) {
    const size_t base = ((size_t)s * 8 + b) * THREED + col;
    qv += g1p[base];
    kc += g1p[base + DMODEL];
    vc += g1p[base + 2 * DMODEL];
  }

  float y = 0.f;
  #pragma unroll 4
  for (int p = 0; p < NPAGES; ++p)
    y += part_y[((size_t)bh * NPAGES + p) * HDIM + d];
  float den = 0.f;
  #pragma unroll 4
  for (int p = 0; p < NPAGES; ++p) den += part_den[bh * NPAGES + p];

  __shared__ float red[HDIM];
  red[d] = qv * kc;
  __syncthreads();
  for (int s = 64; s > 0; s >>= 1) {
    if (d < s) red[d] += red[d + s];
    __syncthreads();
  }
  const float wn = FAST_EXP2(red[0] * SCALE_LOG2E);
  y = (y + wn * vc) / (den + wn);
  yattn[(size_t)b * DMODEL + h * HDIM + d] = y;
}

extern "C" void kernel_launch(void* const* d_in, const int* in_sizes, int n_in,
                              void* d_out, int out_size, void* d_ws,
                              size_t ws_size, hipStream_t stream) {
  const float* x = (const float*)d_in[0];
  const float* k_cache = (const float*)d_in[1];
  const float* v_cache = (const float*)d_in[2];
  const float* w_attn = (const float*)d_in[3];
  const float* b_attn = (const float*)d_in[4];
  const float* w_proj = (const float*)d_in[5];
  const float* b_proj = (const float*)d_in[6];
  float* out = (float*)d_out;
  float* ws = (float*)d_ws;

  // workspace layout (floats)
  float* g1p = ws;                    // 32*8*12288 = 3145728
  float* apy = g1p + 32 * 8 * THREED; // 8192*128   = 1048576
  float* apd = apy + 8192 * HDIM;     // 8192
  float* yat = apd + 8192;            // 8*4096     = 32768
  float* g2p = yat + NB * DMODEL;     // 64*8*4096  = 2097152

  // 1) qkv partials: x @ w_attn  (2 cols/thread, K=4096 split 32x128)
  gemm_skinny_partial<<<dim3(THREED / 512, KSPLIT1), 256, 0, stream>>>(
      x, w_attn, g1p, DMODEL, THREED, 128);

  // 2) paged attention partials (q reduced in-block) + reduce
  attn_partial<<<dim3(NPAGES, NHEAD, NB), 256, 0, stream>>>(
      g1p, b_attn, k_cache, v_cache, apy, apd);
  attn_reduce<<<dim3(NHEAD, NB), 128, 0, stream>>>(
      g1p, b_attn, apy, apd, yat);

  // 3) out = yat @ w_proj + b_proj  (2 cols/thread, K=4096 split 64x64)
  gemm_skinny_partial<<<dim3(DMODEL / 512, 64), 256, 0, stream>>>(
      yat, w_proj, g2p, DMODEL, DMODEL, 64);
  gemm_skinny_reduce<<<dim3(NB * DMODEL / 1024), 256, 0, stream>>>(
      g2p, b_proj, out, DMODEL, 64);
}

// Round 9
// 244.806 us; speedup vs baseline: 1.2725x; 1.0309x over previous
//
#include <hip/hip_runtime.h>
#include <math.h>

#define DMODEL 4096
#define THREED 12288
#define NHEAD 32
#define HDIM 128
#define NB 8
#define NPAGES 32
#define PAGEK 128
#define KSPLIT1 32
#define KSPLIT2 64

#if __has_builtin(__builtin_amdgcn_exp2f)
#define FAST_EXP2(x) __builtin_amdgcn_exp2f(x)
#else
#define FAST_EXP2(x) exp2f(x)
#endif

// log2(e) / sqrt(128)
#define SCALE_LOG2E (0.08838834764831845f * 1.44269504088896340736f)

typedef float f32x4 __attribute__((ext_vector_type(4)));
typedef float f32x2 __attribute__((ext_vector_type(2)));

__device__ __forceinline__ float4 nt_load4(const float* p) {
  f32x4 v = __builtin_nontemporal_load((const f32x4*)p);
  return make_float4(v.x, v.y, v.z, v.w);
}
__device__ __forceinline__ float2 nt_load2(const float* p) {
  f32x2 v = __builtin_nontemporal_load((const f32x2*)p);
  return make_float2(v.x, v.y);
}
__device__ __forceinline__ float nt_load1(const float* p) {
  return __builtin_nontemporal_load(p);
}

// ---------------------------------------------------------------------------
// Skinny GEMM partial: part[s][b][col] = sum_{k in chunk s} X[b][k]*W[k][col]
// X: [8][K] (wave-uniform scalar loads), W: [K][N] row-major, streamed nt.
// Each thread owns 2 columns (float2 loads of W). k-split over blockIdx.y.
// ---------------------------------------------------------------------------
__global__ __launch_bounds__(256) void gemm_skinny_partial(
    const float* __restrict__ X, const float* __restrict__ W,
    float* __restrict__ part, int K, int N, int kchunk) {
  const int col = (blockIdx.x * 256 + threadIdx.x) * 2;
  const int k0 = blockIdx.y * kchunk;

  float2 acc[8];
  #pragma unroll
  for (int b = 0; b < 8; ++b) acc[b] = make_float2(0.f, 0.f);

  const float* wp = W + (size_t)k0 * N + col;
  const float* xp = X + k0;

  #pragma unroll 8
  for (int k = 0; k < kchunk; ++k) {
    const float2 w = nt_load2(wp + (size_t)k * N);
    #pragma unroll
    for (int b = 0; b < 8; ++b) {
      const float xv = xp[b * K + k];  // wave-uniform -> s_load, SGPR operand
      acc[b].x += xv * w.x;
      acc[b].y += xv * w.y;
    }
  }
  #pragma unroll
  for (int b = 0; b < 8; ++b)
    *(float2*)(part + ((size_t)blockIdx.y * 8 + b) * N + col) = acc[b];
}

// out[b][col4] = bias[col4] + sum_s part[s][b][col4]   (float4, nt part reads)
__global__ __launch_bounds__(256) void gemm_skinny_reduce(
    const float* __restrict__ part, const float* __restrict__ bias,
    float* __restrict__ out, int N, int ksplit) {
  int idx = blockIdx.x * 256 + threadIdx.x;  // over 8*N/4
  int n4 = N >> 2;
  int b = idx / n4, col = (idx - b * n4) * 4;
  float4 acc = *(const float4*)(bias + col);
  for (int s = 0; s < ksplit; ++s) {
    const float4 p = nt_load4(part + ((size_t)s * 8 + b) * N + col);
    acc.x += p.x;
    acc.y += p.y;
    acc.z += p.z;
    acc.w += p.w;
  }
  *(float4*)(out + (size_t)b * N + col) = acc;
}

// ---------------------------------------------------------------------------
// Attention partial: one block per (page, head, batch). 256 threads = 4 waves.
// Reads final q from qkv; 16 iters, 2 keys/iter via lane halves, nt float4.
// ---------------------------------------------------------------------------
__global__ __launch_bounds__(256) void attn_partial(
    const float* __restrict__ qkv,      // [8][12288]
    const float* __restrict__ k_cache,  // [32][8][32][128][128]
    const float* __restrict__ v_cache,
    float* __restrict__ part_y,         // [8*32*32][128]
    float* __restrict__ part_den) {     // [8*32*32]
  const int page = blockIdx.x;
  const int h = blockIdx.y;
  const int b = blockIdx.z;
  const int tid = threadIdx.x;
  const int wave = tid >> 6;
  const int lane = tid & 63;
  const int half = lane >> 5;
  const int l31 = lane & 31;

  const float4 qf =
      *(const float4*)(qkv + (size_t)b * THREED + h * HDIM + 4 * l31);

  const size_t base = ((((size_t)page * NB + b) * NHEAD + h) * PAGEK) * HDIM;
  const float* kp = k_cache + base;
  const float* vp = v_cache + base;

  float4 yacc = {0.f, 0.f, 0.f, 0.f};
  float den = 0.f;

  #pragma unroll 4
  for (int i = 0; i < 16; ++i) {
    const int key = wave * 32 + i * 2 + half;
    const float4 kf = nt_load4(kp + key * HDIM + 4 * l31);
    const float4 vf = nt_load4(vp + key * HDIM + 4 * l31);
    float s = qf.x * kf.x + qf.y * kf.y + qf.z * kf.z + qf.w * kf.w;
    s += __shfl_xor(s, 1, 64);
    s += __shfl_xor(s, 2, 64);
    s += __shfl_xor(s, 4, 64);
    s += __shfl_xor(s, 8, 64);
    s += __shfl_xor(s, 16, 64);
    const float w = FAST_EXP2(s * SCALE_LOG2E);
    den += w;
    yacc.x += w * vf.x;
    yacc.y += w * vf.y;
    yacc.z += w * vf.z;
    yacc.w += w * vf.w;
  }

  __shared__ float y_lds[8][HDIM];
  __shared__ float d_lds[8];
  const int row = wave * 2 + half;
  *(float4*)&y_lds[row][4 * l31] = yacc;
  if (l31 == 0) d_lds[row] = den;
  __syncthreads();

  if (tid < HDIM) {
    float y = 0.f;
    #pragma unroll
    for (int r = 0; r < 8; ++r) y += y_lds[r][tid];
    const int bhp = (b * NHEAD + h) * NPAGES + page;
    part_y[(size_t)bhp * HDIM + tid] = y;
    if (tid == 0) {
      float dd = 0.f;
      #pragma unroll
      for (int r = 0; r < 8; ++r) dd += d_lds[r];
      part_den[bhp] = dd;
    }
  }
}

// ---------------------------------------------------------------------------
// Attention reduce: per (b,h) combine 32 page partials + current-token k/v.
// ---------------------------------------------------------------------------
__global__ __launch_bounds__(128) void attn_reduce(
    const float* __restrict__ qkv,
    const float* __restrict__ part_y, const float* __restrict__ part_den,
    float* __restrict__ yattn) {  // [8][4096]
  const int h = blockIdx.x;
  const int b = blockIdx.y;
  const int d = threadIdx.x;
  const int bh = b * NHEAD + h;

  float y = 0.f;
  #pragma unroll 4
  for (int p = 0; p < NPAGES; ++p)
    y += nt_load1(part_y + ((size_t)bh * NPAGES + p) * HDIM + d);
  float den = 0.f;
  #pragma unroll 4
  for (int p = 0; p < NPAGES; ++p)
    den += nt_load1(part_den + bh * NPAGES + p);

  const float q = qkv[(size_t)b * THREED + h * HDIM + d];
  const float kc = qkv[(size_t)b * THREED + DMODEL + h * HDIM + d];
  const float vc = qkv[(size_t)b * THREED + 2 * DMODEL + h * HDIM + d];

  __shared__ float red[HDIM];
  red[d] = q * kc;
  __syncthreads();
  for (int s = 64; s > 0; s >>= 1) {
    if (d < s) red[d] += red[d + s];
    __syncthreads();
  }
  const float wn = FAST_EXP2(red[0] * SCALE_LOG2E);
  y = (y + wn * vc) / (den + wn);
  yattn[(size_t)b * DMODEL + h * HDIM + d] = y;
}

extern "C" void kernel_launch(void* const* d_in, const int* in_sizes, int n_in,
                              void* d_out, int out_size, void* d_ws,
                              size_t ws_size, hipStream_t stream) {
  const float* x = (const float*)d_in[0];
  const float* k_cache = (const float*)d_in[1];
  const float* v_cache = (const float*)d_in[2];
  const float* w_attn = (const float*)d_in[3];
  const float* b_attn = (const float*)d_in[4];
  const float* w_proj = (const float*)d_in[5];
  const float* b_proj = (const float*)d_in[6];
  float* out = (float*)d_out;
  float* ws = (float*)d_ws;

  // workspace layout (floats)
  float* qkv = ws;                          // 8*12288             = 98304
  float* g1p = qkv + 98304;                 // 32*8*12288          = 3145728
  float* apy = g1p + KSPLIT1 * 8 * THREED;  // 8192*128            = 1048576
  float* apd = apy + 8192 * HDIM;           // 8192
  float* yat = apd + 8192;                  // 8*4096              = 32768
  float* g2p = yat + NB * DMODEL;           // 64*8*4096           = 2097152

  // 1) qkv = x @ w_attn + b_attn  (2 cols/thread, K=4096 split 32x128)
  gemm_skinny_partial<<<dim3(THREED / 512, KSPLIT1), 256, 0, stream>>>(
      x, w_attn, g1p, DMODEL, THREED, 128);
  gemm_skinny_reduce<<<dim3(NB * THREED / 1024), 256, 0, stream>>>(
      g1p, b_attn, qkv, THREED, KSPLIT1);

  // 2) paged attention partials + reduce
  attn_partial<<<dim3(NPAGES, NHEAD, NB), 256, 0, stream>>>(
      qkv, k_cache, v_cache, apy, apd);
  attn_reduce<<<dim3(NHEAD, NB), 128, 0, stream>>>(qkv, apy, apd, yat);

  // 3) out = yat @ w_proj + b_proj  (2 cols/thread, K=4096 split 64x64)
  gemm_skinny_partial<<<dim3(DMODEL / 512, KSPLIT2), 256, 0, stream>>>(
      yat, w_proj, g2p, DMODEL, DMODEL, 64);
  gemm_skinny_reduce<<<dim3(NB * DMODEL / 1024), 256, 0, stream>>>(
      g2p, b_proj, out, DMODEL, KSPLIT2);
}